// Round 2
// baseline (849.378 us; speedup 1.0000x reference)
//
#include <hip/hip_runtime.h>
#include <hip/hip_bf16.h>

// ConcatModel (all I/O f32; internal MFMA compute in bf16, f32 accumulate):
// embed-gather(cvt) -> input-proj GEMM -> 64x fused LSTM step (fw+bw batched)
// -> feat concat -> (BN -> GEMM+ReLU) x2 -> BN -> tiny output GEMM.

typedef __attribute__((ext_vector_type(8))) short bf16x8;
typedef __attribute__((ext_vector_type(4))) float f32x4;

#define DEVI __device__ __forceinline__

DEVI void async16(const void* g, void* l) {
  __builtin_amdgcn_global_load_lds((const __attribute__((address_space(1))) void*)g,
                                   (__attribute__((address_space(3))) void*)l,
                                   16, 0, 0);
}
DEVI float sigmf_(float x) { return 1.f / (1.f + __expf(-x)); }
DEVI __hip_bfloat16 f2b(float x) { return __float2bfloat16(x); }

// ---------------------------------------------------------------------------
// generic f32 -> bf16 convert (vectorized: float4 in, 4xbf16 out)
__global__ void cvt_f32_bf16(const float* __restrict__ src,
                             __hip_bfloat16* __restrict__ dst, int n4) {
  int i = blockIdx.x * 256 + threadIdx.x;
  int stride = gridDim.x * 256;
  for (; i < n4; i += stride) {
    float4 v = ((const float4*)src)[i];
    union { __hip_bfloat16 h[4]; uint2 u; } o;
    o.h[0] = f2b(v.x); o.h[1] = f2b(v.y); o.h[2] = f2b(v.z); o.h[3] = f2b(v.w);
    ((uint2*)dst)[i] = o.u;
  }
}

// pack: W_ih f32 [2048][300] -> bf16 [2048][320] (K padded with 0); biasL = b_ih+b_hh
__global__ void pack_wih(const float* __restrict__ W_ih,
                         const float* __restrict__ b_ih,
                         const float* __restrict__ b_hh,
                         __hip_bfloat16* __restrict__ WihP,
                         float* __restrict__ biasL) {
  int tid = blockIdx.x * 256 + threadIdx.x;
  int stride = gridDim.x * 256;
  for (int i = tid; i < 2048 * 320; i += stride) {
    int r = i / 320, c = i - r * 320;
    WihP[i] = (c < 300) ? f2b(W_ih[r * 300 + c]) : f2b(0.f);
  }
  if (tid < 2048) biasL[tid] = b_ih[tid] + b_hh[tid];
}

// ---------------------------------------------------------------------------
// gather+cvt: Ain[m][0..319] bf16, m = t*512 + n; n<256 premise else hypothesis.
__global__ void gather_kernel(const int* __restrict__ prem, const int* __restrict__ hyp,
                              const float* __restrict__ embed,
                              __hip_bfloat16* __restrict__ Ain) {
  int row = blockIdx.x * 4 + (threadIdx.x >> 6);
  int lane = threadIdx.x & 63;
  int tt = row >> 9, n = row & 511;
  int tok = (n < 256) ? prem[tt * 256 + n] : hyp[tt * 256 + (n - 256)];
  const float4* e4 = (const float4*)(embed + (size_t)tok * 300);  // 75 x 16B (1200B row, 16B aligned)
  uint2* d2 = (uint2*)(Ain + (size_t)row * 320);                  // 80 x 8B
  for (int j = lane; j < 75; j += 64) {
    float4 v = e4[j];
    union { __hip_bfloat16 h[4]; uint2 u; } o;
    o.h[0] = f2b(v.x); o.h[1] = f2b(v.y); o.h[2] = f2b(v.z); o.h[3] = f2b(v.w);
    d2[j] = o.u;
  }
  for (int j = 75 + lane; j < 80; j += 64) d2[j] = make_uint2(0u, 0u);
}

// ---------------------------------------------------------------------------
// GEMM: C[M][N] = A[M][K] * Bn[N][K]^T (+bias). A,Bn bf16 row-major (ld=K).
// BM x 128 tile, BK=64, 4 waves 2x2, 16x16x32 bf16 MFMA, global_load_lds staging
// with pre-swizzled source (rule #21: linear LDS dest + inverse-swizzled source
// + swizzled read), double-buffered LDS.
// EPI=0: bf16 out + bias.  EPI=1: f32 out + bias + relu.
template<int BM, int EPI>
__global__ __launch_bounds__(256)
void gemm_kernel(const __hip_bfloat16* __restrict__ A,
                 const __hip_bfloat16* __restrict__ Bn,
                 const float* __restrict__ bias,
                 void* __restrict__ Cout,
                 int K, int ldc) {
  constexpr int BN = 128, BK = 64;
  constexpr int WM = BM / 2, WN = 64;
  constexpr int MT = WM / 16, NT = WN / 16;
  constexpr int AISS = BM / 8;   // 8-row (1KB) chunks per A tile
  constexpr int BISS = BN / 8;
  constexpr int APW = AISS / 4, BPW = BISS / 4;

  __shared__ alignas(16) __hip_bfloat16 Asm[2][BM * BK];
  __shared__ alignas(16) __hip_bfloat16 Bsm[2][BN * BK];

  const int tid = threadIdx.x;
  const int lane = tid & 63, wid = tid >> 6;
  const int wrow = wid >> 1, wcol = wid & 1;
  const int m0 = blockIdx.x * BM, n0 = blockIdx.y * BN;

  const int l8 = lane & 7, ld8 = lane >> 3;
  const int swz = (l8 ^ ld8) * 8;  // pre-swizzled source col (elems)

  const __hip_bfloat16* Abase = A + (size_t)m0 * K;
  const __hip_bfloat16* Bbase = Bn + (size_t)n0 * K;

  f32x4 acc[MT][NT];
#pragma unroll
  for (int i = 0; i < MT; ++i)
#pragma unroll
    for (int j = 0; j < NT; ++j) acc[i][j] = {0.f, 0.f, 0.f, 0.f};

  auto stage = [&](int buf, int kt) {
    const __hip_bfloat16* as = Abase + kt * BK + swz;
#pragma unroll
    for (int s = 0; s < APW; ++s) {
      int iss = wid * APW + s;
      async16(as + (size_t)(iss * 8 + ld8) * K, &Asm[buf][iss * 512]);
    }
    const __hip_bfloat16* bs = Bbase + kt * BK + swz;
#pragma unroll
    for (int s = 0; s < BPW; ++s) {
      int iss = wid * BPW + s;
      async16(bs + (size_t)(iss * 8 + ld8) * K, &Bsm[buf][iss * 512]);
    }
  };

  const int nk = K / BK;
  stage(0, 0);
  __syncthreads();
  int cur = 0;
  for (int kt = 0; kt < nk; ++kt) {
    if (kt + 1 < nk) stage(cur ^ 1, kt + 1);
#pragma unroll
    for (int kk = 0; kk < BK; kk += 32) {
      bf16x8 af[MT], bfr[NT];
#pragma unroll
      for (int i = 0; i < MT; ++i) {
        int r = wrow * WM + i * 16 + (lane & 15);
        int off = r * BK + ((kk + (lane >> 4) * 8) ^ ((r & 7) * 8));
        af[i] = *(const bf16x8*)&Asm[cur][off];
      }
#pragma unroll
      for (int j = 0; j < NT; ++j) {
        int r = wcol * WN + j * 16 + (lane & 15);
        int off = r * BK + ((kk + (lane >> 4) * 8) ^ ((r & 7) * 8));
        bfr[j] = *(const bf16x8*)&Bsm[cur][off];
      }
#pragma unroll
      for (int i = 0; i < MT; ++i)
#pragma unroll
        for (int j = 0; j < NT; ++j)
          acc[i][j] = __builtin_amdgcn_mfma_f32_16x16x32_bf16(af[i], bfr[j], acc[i][j], 0, 0, 0);
    }
    __syncthreads();
    cur ^= 1;
  }

#pragma unroll
  for (int i = 0; i < MT; ++i)
#pragma unroll
    for (int j = 0; j < NT; ++j) {
      int gcol = n0 + wcol * WN + j * 16 + (lane & 15);
      float bv = bias[gcol];
#pragma unroll
      for (int r = 0; r < 4; ++r) {
        int grow = m0 + wrow * WM + i * 16 + (lane >> 4) * 4 + r;
        float v = acc[i][j][r] + bv;
        if (EPI == 0) {
          ((__hip_bfloat16*)Cout)[(size_t)grow * ldc + gcol] = f2b(v);
        } else {
          ((float*)Cout)[(size_t)grow * ldc + gcol] = fmaxf(v, 0.f);
        }
      }
    }
}

// ---------------------------------------------------------------------------
// One LSTM time step, fw (rows 0..511) + bw (rows 512..1023) batched.
// grid (16 mtiles x 16 jtiles). Per wg: gate tile [64 rows][4 gates x 32 cols],
// K=512 MFMA vs bf16 W_hh (native [2048][512] layout), then fused pointwise.
__global__ __launch_bounds__(256)
void lstm_step_kernel(const __hip_bfloat16* __restrict__ xp,
                      const __hip_bfloat16* __restrict__ hin,
                      __hip_bfloat16* __restrict__ hout,
                      float* __restrict__ cst,
                      const __hip_bfloat16* __restrict__ Whh,
                      int t) {
  constexpr int BK = 64;
  __shared__ alignas(16) char smem[49152];
  __hip_bfloat16* Asm = (__hip_bfloat16*)smem;            // [2][64*64]  = 16 KB
  __hip_bfloat16* Bsm = (__hip_bfloat16*)(smem + 16384);  // [2][128*64] = 32 KB
  float* gsm = (float*)smem;                              // [64][128] after K-loop (aliases)

  const int tid = threadIdx.x;
  const int lane = tid & 63, wid = tid >> 6;
  const int m0 = blockIdx.x * 64;
  const int jt = blockIdx.y;  // 32 h-columns

  const int l8 = lane & 7, ld8 = lane >> 3;
  const int swz = (l8 ^ ld8) * 8;

  auto stage = [&](int buf, int kt) {
    const __hip_bfloat16* as = hin + (size_t)m0 * 512 + kt * BK + swz;
#pragma unroll
    for (int s = 0; s < 2; ++s) {
      int iss = wid * 2 + s;
      async16(as + (size_t)(iss * 8 + ld8) * 512, &Asm[buf * 4096 + iss * 512]);
    }
    const __hip_bfloat16* bs = Whh + kt * BK + swz;
#pragma unroll
    for (int s = 0; s < 4; ++s) {
      int iss = wid * 4 + s;
      int r = iss * 8 + ld8;                        // 0..127 tile row
      int g = jt * 32 + (r >> 5) * 512 + (r & 31);  // gate col: chunks i,f,g,o
      async16(bs + (size_t)g * 512, &Bsm[buf * 8192 + iss * 512]);
    }
  };

  f32x4 acc[4][2];
#pragma unroll
  for (int i = 0; i < 4; ++i)
#pragma unroll
    for (int j = 0; j < 2; ++j) acc[i][j] = {0.f, 0.f, 0.f, 0.f};

  stage(0, 0);
  __syncthreads();
  int cur = 0;
  for (int kt = 0; kt < 8; ++kt) {
    if (kt < 7) stage(cur ^ 1, kt + 1);
#pragma unroll
    for (int kk = 0; kk < BK; kk += 32) {
      bf16x8 af[4], bfr[2];
#pragma unroll
      for (int i = 0; i < 4; ++i) {
        int r = i * 16 + (lane & 15);
        int off = r * BK + ((kk + (lane >> 4) * 8) ^ ((r & 7) * 8));
        af[i] = *(const bf16x8*)&Asm[cur * 4096 + off];
      }
#pragma unroll
      for (int j = 0; j < 2; ++j) {
        int r = wid * 32 + j * 16 + (lane & 15);
        int off = r * BK + ((kk + (lane >> 4) * 8) ^ ((r & 7) * 8));
        bfr[j] = *(const bf16x8*)&Bsm[cur * 8192 + off];
      }
#pragma unroll
      for (int i = 0; i < 4; ++i)
#pragma unroll
        for (int j = 0; j < 2; ++j)
          acc[i][j] = __builtin_amdgcn_mfma_f32_16x16x32_bf16(af[i], bfr[j], acc[i][j], 0, 0, 0);
    }
    __syncthreads();
    cur ^= 1;
  }

  // gates -> LDS (stage buffers dead after final barrier)
#pragma unroll
  for (int i = 0; i < 4; ++i)
#pragma unroll
    for (int j = 0; j < 2; ++j)
#pragma unroll
      for (int r = 0; r < 4; ++r) {
        int row = i * 16 + (lane >> 4) * 4 + r;
        int col = wid * 32 + j * 16 + (lane & 15);
        gsm[row * 128 + col] = acc[i][j][r];
      }
  __syncthreads();

  // fused pointwise: c' = sig(f)*c + sig(i)*tanh(g); h' = sig(o)*tanh(c')
#pragma unroll
  for (int e = 0; e < 8; ++e) {
    int idx = e * 256 + tid;
    int r = idx >> 5, jc = idx & 31;
    int gm = m0 + r;
    int gj = jt * 32 + jc;
    size_t xrow = (gm < 512) ? ((size_t)t * 512 + gm) : ((size_t)(63 - t) * 512 + (gm - 512));
    const __hip_bfloat16* xr = xp + xrow * 2048 + jt * 32 + jc;
    float gi = gsm[r * 128 + jc]      + __bfloat162float(xr[0]);
    float gf = gsm[r * 128 + 32 + jc] + __bfloat162float(xr[512]);
    float gg = gsm[r * 128 + 64 + jc] + __bfloat162float(xr[1024]);
    float go = gsm[r * 128 + 96 + jc] + __bfloat162float(xr[1536]);
    size_t ci = (size_t)gm * 512 + gj;
    float cn = sigmf_(gf) * cst[ci] + sigmf_(gi) * tanhf(gg);
    float hn = sigmf_(go) * tanhf(cn);
    cst[ci] = cn;
    hout[ci] = f2b(hn);
  }
}

// ---------------------------------------------------------------------------
// feat[b][c]: cols [0:512)=h_fw[b], [512:1024)=h_bw[b], [1024:1536)=h_fw[256+b],
// [1536:2048)=h_bw[256+b].  fw rows 0..511, bw rows 512..1023 of h.
__global__ void feat_kernel(const __hip_bfloat16* __restrict__ hA, float* __restrict__ feat) {
  int b = blockIdx.x;
  for (int c = threadIdx.x; c < 2048; c += 256) {
    int sec = c >> 9, j = c & 511;
    int row = (sec == 0) ? b : (sec == 1) ? 512 + b : (sec == 2) ? 256 + b : 768 + b;
    feat[b * 2048 + c] = __bfloat162float(hA[(size_t)row * 512 + j]);
  }
}

// BatchNorm1d training-mode stats (biased var) folded into scale/shift (f32 params)
__global__ void bn_stats(const float* __restrict__ x, const float* __restrict__ g,
                         const float* __restrict__ b,
                         float* __restrict__ sc, float* __restrict__ sh) {
  int c = blockIdx.x * 256 + threadIdx.x;  // 2048 cols
  float s = 0.f, s2 = 0.f;
  for (int r = 0; r < 256; ++r) {
    float v = x[r * 2048 + c];
    s += v;
    s2 += v * v;
  }
  float mu = s * (1.f / 256.f);
  float var = s2 * (1.f / 256.f) - mu * mu;
  float rs = rsqrtf(var + 1e-5f);
  float scale = g[c] * rs;
  sc[c] = scale;
  sh[c] = b[c] - mu * scale;
}

__global__ void bn_apply(const float* __restrict__ x, const float* __restrict__ sc,
                         const float* __restrict__ sh, __hip_bfloat16* __restrict__ xn) {
  int i = blockIdx.x * 256 + threadIdx.x;  // 256*2048
  int c = i & 2047;
  xn[i] = f2b(x[i] * sc[c] + sh[c]);
}

// out[b][d] = sum_c bn(x2)[b][c] * Wo[d][c] + bo[d]   (all f32)
__global__ void final_kernel(const float* __restrict__ x2, const float* __restrict__ sc,
                             const float* __restrict__ sh, const float* __restrict__ Wo,
                             const float* __restrict__ bo, float* __restrict__ out) {
  __shared__ float red[3][256];
  int b = blockIdx.x, tid = threadIdx.x;
  float a0 = 0.f, a1 = 0.f, a2 = 0.f;
  for (int c = tid; c < 2048; c += 256) {
    float v = x2[b * 2048 + c] * sc[c] + sh[c];
    a0 += v * Wo[c];
    a1 += v * Wo[2048 + c];
    a2 += v * Wo[4096 + c];
  }
  red[0][tid] = a0; red[1][tid] = a1; red[2][tid] = a2;
  __syncthreads();
  for (int s = 128; s > 0; s >>= 1) {
    if (tid < s) {
      red[0][tid] += red[0][tid + s];
      red[1][tid] += red[1][tid + s];
      red[2][tid] += red[2][tid + s];
    }
    __syncthreads();
  }
  if (tid < 3) out[b * 3 + tid] = red[tid][0] + bo[tid];
}

// ---------------------------------------------------------------------------
extern "C" void kernel_launch(void* const* d_in, const int* in_sizes, int n_in,
                              void* d_out, int out_size, void* d_ws, size_t ws_size,
                              hipStream_t stream) {
  (void)in_sizes; (void)n_in; (void)out_size; (void)ws_size;
  const int* prem = (const int*)d_in[0];
  const int* hyp = (const int*)d_in[1];
  const float* embed = (const float*)d_in[2];
  const float* W_ih = (const float*)d_in[3];
  const float* W_hh = (const float*)d_in[4];
  const float* b_ih = (const float*)d_in[5];
  const float* b_hh = (const float*)d_in[6];
  const float* bn0g = (const float*)d_in[7];
  const float* bn0b = (const float*)d_in[8];
  const float* W0 = (const float*)d_in[9];
  const float* b0 = (const float*)d_in[10];
  const float* bn1g = (const float*)d_in[11];
  const float* bn1b = (const float*)d_in[12];
  const float* W1 = (const float*)d_in[13];
  const float* b1 = (const float*)d_in[14];
  const float* bnog = (const float*)d_in[15];
  const float* bnob = (const float*)d_in[16];
  const float* Wo = (const float*)d_in[17];
  const float* bo = (const float*)d_in[18];
  float* out = (float*)d_out;

  char* w = (char*)d_ws;
  size_t off = 0;
  auto alloc = [&](size_t bytes) {
    void* p = w + off;
    off += (bytes + 255) & ~(size_t)255;
    return p;
  };
  // persistent-through-launch buffers
  __hip_bfloat16* WihP = (__hip_bfloat16*)alloc((size_t)2048 * 320 * 2);
  __hip_bfloat16* Whhb = (__hip_bfloat16*)alloc((size_t)2048 * 512 * 2);
  __hip_bfloat16* W0b = (__hip_bfloat16*)alloc((size_t)2048 * 2048 * 2);
  __hip_bfloat16* W1b = (__hip_bfloat16*)alloc((size_t)2048 * 2048 * 2);
  float* biasL = (float*)alloc(2048 * 4);
  __hip_bfloat16* xp = (__hip_bfloat16*)alloc((size_t)32768 * 2048 * 2);  // 128 MiB
  // Ain is dead after the x-proj GEMM; overlap all post-GEMM buffers into it.
  size_t ain_off = off;
  __hip_bfloat16* Ain = (__hip_bfloat16*)alloc((size_t)32768 * 320 * 2);  // 20 MiB
  size_t end_off = off;
  off = ain_off;  // rewind: post-GEMM block aliases Ain (11.6 MiB < 20 MiB)
  __hip_bfloat16* hA = (__hip_bfloat16*)alloc((size_t)1024 * 512 * 2);
  __hip_bfloat16* hB = (__hip_bfloat16*)alloc((size_t)1024 * 512 * 2);
  float* cst = (float*)alloc((size_t)1024 * 512 * 4);
  float* feat = (float*)alloc((size_t)256 * 2048 * 4);
  __hip_bfloat16* xn = (__hip_bfloat16*)alloc((size_t)256 * 2048 * 2);
  float* x1 = (float*)alloc((size_t)256 * 2048 * 4);
  float* x2 = (float*)alloc((size_t)256 * 2048 * 4);
  float* sc0 = (float*)alloc(2048 * 4);
  float* sh0 = (float*)alloc(2048 * 4);
  float* sc1 = (float*)alloc(2048 * 4);
  float* sh1 = (float*)alloc(2048 * 4);
  float* sc2 = (float*)alloc(2048 * 4);
  float* sh2 = (float*)alloc(2048 * 4);
  (void)end_off;  // peak = max(end_off, off) ~= 175 MiB

  // weight conversions (run every launch; ~50MB traffic)
  pack_wih<<<512, 256, 0, stream>>>(W_ih, b_ih, b_hh, WihP, biasL);
  cvt_f32_bf16<<<1024, 256, 0, stream>>>(W_hh, Whhb, 2048 * 512 / 4);
  cvt_f32_bf16<<<2048, 256, 0, stream>>>(W0, W0b, 2048 * 2048 / 4);
  cvt_f32_bf16<<<2048, 256, 0, stream>>>(W1, W1b, 2048 * 2048 / 4);
  gather_kernel<<<8192, 256, 0, stream>>>(prem, hyp, embed, Ain);
  // x_proj = combined @ W_ih^T + (b_ih + b_hh) : M=32768, N=2048, K=320
  gemm_kernel<128, 0><<<dim3(256, 16), 256, 0, stream>>>(Ain, WihP, biasL, xp, 320, 2048);
  // init h0/c0 AFTER the GEMM (hA/cst alias Ain's region)
  hipMemsetAsync(hA, 0, (size_t)1024 * 512 * 2, stream);
  hipMemsetAsync(cst, 0, (size_t)1024 * 512 * 4, stream);
  // 64 sequential steps, fw+bw batched; h double-buffered
  for (int t = 0; t < 64; ++t) {
    const __hip_bfloat16* hi = (t & 1) ? hB : hA;
    __hip_bfloat16* ho = (t & 1) ? hA : hB;
    lstm_step_kernel<<<dim3(16, 16), 256, 0, stream>>>(xp, hi, ho, cst, Whhb, t);
  }
  feat_kernel<<<256, 256, 0, stream>>>(hA, feat);  // final h in hA (t=63 odd)
  bn_stats<<<8, 256, 0, stream>>>(feat, bn0g, bn0b, sc0, sh0);
  bn_apply<<<2048, 256, 0, stream>>>(feat, sc0, sh0, xn);
  gemm_kernel<64, 1><<<dim3(4, 16), 256, 0, stream>>>(xn, W0b, b0, x1, 2048, 2048);
  bn_stats<<<8, 256, 0, stream>>>(x1, bn1g, bn1b, sc1, sh1);
  bn_apply<<<2048, 256, 0, stream>>>(x1, sc1, sh1, xn);
  gemm_kernel<64, 1><<<dim3(4, 16), 256, 0, stream>>>(xn, W1b, b1, x2, 2048, 2048);
  bn_stats<<<8, 256, 0, stream>>>(x2, bnog, bnob, sc2, sh2);
  final_kernel<<<256, 256, 0, stream>>>(x2, sc2, sh2, Wo, bo, out);
}

// Round 3
// 641.178 us; speedup vs baseline: 1.3247x; 1.3247x over previous
//
#include <hip/hip_runtime.h>
#include <hip/hip_bf16.h>

// ConcatModel (all I/O f32; internal MFMA compute bf16, f32 accumulate):
// embed-gather(cvt) -> input-proj GEMM (pipelined) -> 64x fused LSTM step
// (counted-vmcnt pipeline, xp prefetch) -> feat -> (BN -> GEMM+ReLU) x2 -> BN -> out.

typedef __attribute__((ext_vector_type(8))) short bf16x8;
typedef __attribute__((ext_vector_type(4))) float f32x4;

#define DEVI __device__ __forceinline__

DEVI void async16(const void* g, void* l) {
  __builtin_amdgcn_global_load_lds((const __attribute__((address_space(1))) void*)g,
                                   (__attribute__((address_space(3))) void*)l,
                                   16, 0, 0);
}
// per-wave counted wait for own outstanding loads, then align all waves.
// (vmcnt(N) -> s_barrier: each wave verifies its own tile-k loads landed before
//  arriving; after the barrier the tile is collectively ready. Never 0 mid-loop.)
template<int N> DEVI void vmwait_barrier() {
  asm volatile("s_waitcnt vmcnt(%0)" ::"i"(N) : "memory");
  __builtin_amdgcn_s_barrier();
  __builtin_amdgcn_sched_barrier(0);
}
DEVI float sigmf_(float x) { return 1.f / (1.f + __expf(-x)); }
DEVI float tanhf_(float x) {
  float a = __expf(-2.f * fabsf(x));
  float t = (1.f - a) / (1.f + a);
  return copysignf(t, x);
}
DEVI __hip_bfloat16 f2b(float x) { return __float2bfloat16(x); }
DEVI float b2f(__hip_bfloat16 x) { return __bfloat162float(x); }

// ---------------------------------------------------------------------------
__global__ void cvt_f32_bf16(const float* __restrict__ src,
                             __hip_bfloat16* __restrict__ dst, int n4) {
  int i = blockIdx.x * 256 + threadIdx.x;
  int stride = gridDim.x * 256;
  for (; i < n4; i += stride) {
    float4 v = ((const float4*)src)[i];
    union { __hip_bfloat16 h[4]; uint2 u; } o;
    o.h[0] = f2b(v.x); o.h[1] = f2b(v.y); o.h[2] = f2b(v.z); o.h[3] = f2b(v.w);
    ((uint2*)dst)[i] = o.u;
  }
}

__global__ void pack_wih(const float* __restrict__ W_ih,
                         const float* __restrict__ b_ih,
                         const float* __restrict__ b_hh,
                         __hip_bfloat16* __restrict__ WihP,
                         float* __restrict__ biasL) {
  int tid = blockIdx.x * 256 + threadIdx.x;
  int stride = gridDim.x * 256;
  for (int i = tid; i < 2048 * 320; i += stride) {
    int r = i / 320, c = i - r * 320;
    WihP[i] = (c < 300) ? f2b(W_ih[r * 300 + c]) : f2b(0.f);
  }
  if (tid < 2048) biasL[tid] = b_ih[tid] + b_hh[tid];
}

// gather+cvt: Ain[m][0..319] bf16, m = t*512 + n; n<256 premise else hypothesis.
__global__ void gather_kernel(const int* __restrict__ prem, const int* __restrict__ hyp,
                              const float* __restrict__ embed,
                              __hip_bfloat16* __restrict__ Ain) {
  int row = blockIdx.x * 4 + (threadIdx.x >> 6);
  int lane = threadIdx.x & 63;
  int tt = row >> 9, n = row & 511;
  int tok = (n < 256) ? prem[tt * 256 + n] : hyp[tt * 256 + (n - 256)];
  const float4* e4 = (const float4*)(embed + (size_t)tok * 300);  // 75 x 16B
  uint2* d2 = (uint2*)(Ain + (size_t)row * 320);                  // 80 x 8B
  for (int j = lane; j < 75; j += 64) {
    float4 v = e4[j];
    union { __hip_bfloat16 h[4]; uint2 u; } o;
    o.h[0] = f2b(v.x); o.h[1] = f2b(v.y); o.h[2] = f2b(v.z); o.h[3] = f2b(v.w);
    d2[j] = o.u;
  }
  for (int j = 75 + lane; j < 80; j += 64) d2[j] = make_uint2(0u, 0u);
}

// ---------------------------------------------------------------------------
// Pipelined GEMM: C[M][N=128/blk] = A[M][K] * Bn[N][K]^T (+bias).
// BM x 128 tile, BK=64, 4 waves 2x2. Counted-vmcnt double-barrier K-loop
// (lookahead-1, 2 LDS bufs) + LDS-bounce coalesced epilogue.
// EPI=0: bf16 out.  EPI=1: f32 out + relu.
template<int BM, int EPI>
__global__ __launch_bounds__(256)
void gemm_pipe(const __hip_bfloat16* __restrict__ A,
               const __hip_bfloat16* __restrict__ Bn,
               const float* __restrict__ bias,
               void* __restrict__ Cout, int K, int ldc) {
  constexpr int BK = 64;
  constexpr int ABYT = BM * BK * 2;
  constexpr int BBYT = 128 * BK * 2;
  constexpr int APW = BM / 32;     // A stage-issues per wave
  constexpr int IFL = APW + 4;     // per-wave issues per tile (A+B)
  constexpr int WM = BM / 2, MT = WM / 16;
  __shared__ alignas(16) char smem[2 * ABYT + 2 * BBYT];

  const int tid = threadIdx.x, lane = tid & 63, wid = tid >> 6;
  const int wrow = wid >> 1, wcol = wid & 1;
  const int m0 = blockIdx.x * BM, n0 = blockIdx.y * 128;
  const int l8 = lane & 7, ld8 = lane >> 3;
  const int swz = (l8 ^ ld8) * 8;  // pre-swizzled source col (rule #21)

  const __hip_bfloat16* Abase = A + (size_t)m0 * K;
  const __hip_bfloat16* Bbase = Bn + (size_t)n0 * K;

  f32x4 acc[MT][4];
#pragma unroll
  for (int i = 0; i < MT; ++i)
#pragma unroll
    for (int j = 0; j < 4; ++j) acc[i][j] = {0.f, 0.f, 0.f, 0.f};

  auto stage = [&](int buf, int kt) {
    const __hip_bfloat16* as = Abase + kt * BK + swz;
    char* ad = smem + buf * ABYT;
#pragma unroll
    for (int s = 0; s < APW; ++s) {
      int iss = wid * APW + s;
      async16(as + (size_t)(iss * 8 + ld8) * K, ad + iss * 1024);
    }
    const __hip_bfloat16* bs = Bbase + kt * BK + swz;
    char* bd = smem + 2 * ABYT + buf * BBYT;
#pragma unroll
    for (int s = 0; s < 4; ++s) {
      int iss = wid * 4 + s;
      async16(bs + (size_t)(iss * 8 + ld8) * K, bd + iss * 1024);
    }
  };

  const int nk = K / BK;
  stage(0, 0);
  for (int kt = 0; kt < nk; ++kt) {
    if (kt + 1 < nk) {
      stage((kt + 1) & 1, kt + 1);
      vmwait_barrier<IFL>();
    } else {
      vmwait_barrier<0>();
    }
    const __hip_bfloat16* ab = (const __hip_bfloat16*)(smem + (kt & 1) * ABYT);
    const __hip_bfloat16* bb = (const __hip_bfloat16*)(smem + 2 * ABYT + (kt & 1) * BBYT);
#pragma unroll
    for (int kk = 0; kk < BK; kk += 32) {
      bf16x8 af[MT], bf[4];
#pragma unroll
      for (int i = 0; i < MT; ++i) {
        int r = wrow * WM + i * 16 + (lane & 15);
        af[i] = *(const bf16x8*)&ab[r * BK + ((kk + (lane >> 4) * 8) ^ ((r & 7) * 8))];
      }
#pragma unroll
      for (int j = 0; j < 4; ++j) {
        int r = wcol * 64 + j * 16 + (lane & 15);
        bf[j] = *(const bf16x8*)&bb[r * BK + ((kk + (lane >> 4) * 8) ^ ((r & 7) * 8))];
      }
#pragma unroll
      for (int i = 0; i < MT; ++i)
#pragma unroll
        for (int j = 0; j < 4; ++j)
          acc[i][j] = __builtin_amdgcn_mfma_f32_16x16x32_bf16(af[i], bf[j], acc[i][j], 0, 0, 0);
    }
    __builtin_amdgcn_s_barrier();  // protect bufs from next iteration's stage
  }
  __syncthreads();

  // LDS bounce: acc -> Csm (XOR-swizzled) -> coalesced 16B stores
  float* Csm = (float*)smem;  // BM*128*4 <= blob size
#pragma unroll
  for (int i = 0; i < MT; ++i)
#pragma unroll
    for (int j = 0; j < 4; ++j)
#pragma unroll
      for (int rr = 0; rr < 4; ++rr) {
        int row = wrow * WM + i * 16 + (lane >> 4) * 4 + rr;
        int col = wcol * 64 + j * 16 + (lane & 15);
        Csm[row * 128 + (col ^ ((row & 3) << 4))] = acc[i][j][rr];
      }
  __syncthreads();
#pragma unroll
  for (int it = 0; it < BM / 16; ++it) {
    int idx = it * 256 + tid;
    int row = idx >> 4;
    int cb = (idx & 15) * 8;
    int pc = cb ^ ((row & 3) << 4);
    float4 v0 = *(const float4*)&Csm[row * 128 + pc];
    float4 v1 = *(const float4*)&Csm[row * 128 + pc + 4];
    float4 b0 = *(const float4*)&bias[n0 + cb];
    float4 b1 = *(const float4*)&bias[n0 + cb + 4];
    v0.x += b0.x; v0.y += b0.y; v0.z += b0.z; v0.w += b0.w;
    v1.x += b1.x; v1.y += b1.y; v1.z += b1.z; v1.w += b1.w;
    size_t base = (size_t)(m0 + row) * ldc + n0 + cb;
    if (EPI == 0) {
      union { __hip_bfloat16 h[8]; uint4 u; } o;
      o.h[0] = f2b(v0.x); o.h[1] = f2b(v0.y); o.h[2] = f2b(v0.z); o.h[3] = f2b(v0.w);
      o.h[4] = f2b(v1.x); o.h[5] = f2b(v1.y); o.h[6] = f2b(v1.z); o.h[7] = f2b(v1.w);
      *(uint4*)&((__hip_bfloat16*)Cout)[base] = o.u;
    } else {
      v0.x = fmaxf(v0.x, 0.f); v0.y = fmaxf(v0.y, 0.f);
      v0.z = fmaxf(v0.z, 0.f); v0.w = fmaxf(v0.w, 0.f);
      v1.x = fmaxf(v1.x, 0.f); v1.y = fmaxf(v1.y, 0.f);
      v1.z = fmaxf(v1.z, 0.f); v1.w = fmaxf(v1.w, 0.f);
      *(float4*)&((float*)Cout)[base] = v0;
      *(float4*)&((float*)Cout)[base + 4] = v1;
    }
  }
}

// ---------------------------------------------------------------------------
// One LSTM time step, fw (rows 0..511) + bw (512..1023) batched.
// grid (16 mt x 16 jt); per wg: 64 rows x (4 gates x 32 h-cols), K=512.
// 3-buf lookahead-2 counted-vmcnt pipeline; xp gate slice prefetched to LDS.
// LDS map: A 3x8KB @0 | W 3x16KB @24K | xsm 16KB @72K ; gsm f32 32KB aliases @0.
__global__ __launch_bounds__(256)
void lstm_step(const __hip_bfloat16* __restrict__ xp,
               const __hip_bfloat16* __restrict__ hin,
               __hip_bfloat16* __restrict__ hout,
               float* __restrict__ cst,
               const __hip_bfloat16* __restrict__ Whh,
               int t) {
  __shared__ alignas(16) char smem[90112];
  const int tid = threadIdx.x, lane = tid & 63, wid = tid >> 6;
  const int mt = blockIdx.x, jt = blockIdx.y;
  const int m0 = mt * 64;
  const int l8 = lane & 7, ld8 = lane >> 3;
  const int swz = (l8 ^ ld8) * 8;

  // xp prefetch FIRST (latency hides under the whole K-loop): 4 issues/wave.
  // unit u = iss*64+lane -> r=u>>4, g=(lane>>2)&3, c8=lane&3; xsm linear [r][g][c8].
  {
    const int rowbase = (mt < 8) ? (t * 512 + m0) : ((63 - t) * 512 + (m0 - 512));
#pragma unroll
    for (int s = 0; s < 4; ++s) {
      int iss = wid * 4 + s;
      const __hip_bfloat16* src = xp + (size_t)(rowbase + iss * 4 + (lane >> 4)) * 2048 +
                                  ((lane >> 2) & 3) * 512 + jt * 32 + (lane & 3) * 8;
      async16(src, smem + 73728 + iss * 1024);
    }
  }
  auto stageA = [&](int buf, int kt) {
#pragma unroll
    for (int s = 0; s < 2; ++s) {
      int iss = wid * 2 + s;
      async16(hin + (size_t)(m0 + iss * 8 + ld8) * 512 + kt * 64 + swz,
              smem + buf * 8192 + iss * 1024);
    }
  };
  auto stageW = [&](int buf, int kt) {
#pragma unroll
    for (int s = 0; s < 4; ++s) {
      int iss = wid * 4 + s;
      int r = iss * 8 + ld8;
      int g = jt * 32 + (r >> 5) * 512 + (r & 31);  // gate-chunk layout i,f,g,o
      async16(Whh + (size_t)g * 512 + kt * 64 + swz,
              smem + 24576 + buf * 16384 + iss * 1024);
    }
  };

  f32x4 acc[4][2];
#pragma unroll
  for (int i = 0; i < 4; ++i)
#pragma unroll
    for (int j = 0; j < 2; ++j) acc[i][j] = {0.f, 0.f, 0.f, 0.f};

  stageA(0, 0); stageW(0, 0);
  stageA(1, 1); stageW(1, 1);
#pragma unroll
  for (int kt = 0; kt < 8; ++kt) {
    if (kt < 6) { stageA((kt + 2) % 3, kt + 2); stageW((kt + 2) % 3, kt + 2); }
    if (kt < 6) vmwait_barrier<12>();       // 2 future tiles (6 issues each) in flight
    else if (kt == 6) vmwait_barrier<6>();
    else vmwait_barrier<0>();
    const __hip_bfloat16* ab = (const __hip_bfloat16*)(smem + (kt % 3) * 8192);
    const __hip_bfloat16* wb = (const __hip_bfloat16*)(smem + 24576 + (kt % 3) * 16384);
#pragma unroll
    for (int kk = 0; kk < 64; kk += 32) {
      bf16x8 af[4], bf[2];
#pragma unroll
      for (int i = 0; i < 4; ++i) {
        int r = i * 16 + (lane & 15);
        af[i] = *(const bf16x8*)&ab[r * 64 + ((kk + (lane >> 4) * 8) ^ ((r & 7) * 8))];
      }
#pragma unroll
      for (int j = 0; j < 2; ++j) {
        int r = wid * 32 + j * 16 + (lane & 15);
        bf[j] = *(const bf16x8*)&wb[r * 64 + ((kk + (lane >> 4) * 8) ^ ((r & 7) * 8))];
      }
#pragma unroll
      for (int i = 0; i < 4; ++i)
#pragma unroll
        for (int j = 0; j < 2; ++j)
          acc[i][j] = __builtin_amdgcn_mfma_f32_16x16x32_bf16(af[i], bf[j], acc[i][j], 0, 0, 0);
    }
    __builtin_amdgcn_s_barrier();  // protect bufs from next iteration's stage
  }
  __syncthreads();

  // gate exchange (gsm aliases A/W bufs; xsm untouched)
  float* gsm = (float*)smem;
#pragma unroll
  for (int i = 0; i < 4; ++i)
#pragma unroll
    for (int j = 0; j < 2; ++j)
#pragma unroll
      for (int rr = 0; rr < 4; ++rr) {
        int row = i * 16 + (lane >> 4) * 4 + rr;
        int col = wid * 32 + j * 16 + (lane & 15);
        gsm[row * 128 + col] = acc[i][j][rr];
      }
  __syncthreads();

  const __hip_bfloat16* xsm = (const __hip_bfloat16*)(smem + 73728);
#pragma unroll
  for (int e = 0; e < 8; ++e) {
    int idx = e * 256 + tid;
    int r = idx >> 5, jc = idx & 31;
    int gm = m0 + r, gj = jt * 32 + jc;
    float gi = gsm[r * 128 + jc]      + b2f(xsm[(r * 4 + 0) * 32 + jc]);
    float gf = gsm[r * 128 + 32 + jc] + b2f(xsm[(r * 4 + 1) * 32 + jc]);
    float gg = gsm[r * 128 + 64 + jc] + b2f(xsm[(r * 4 + 2) * 32 + jc]);
    float go = gsm[r * 128 + 96 + jc] + b2f(xsm[(r * 4 + 3) * 32 + jc]);
    size_t ci = (size_t)gm * 512 + gj;
    float cn = sigmf_(gf) * cst[ci] + sigmf_(gi) * tanhf_(gg);
    float hn = sigmf_(go) * tanhf_(cn);
    cst[ci] = cn;
    hout[ci] = f2b(hn);
  }
}

// ---------------------------------------------------------------------------
__global__ void feat_kernel(const __hip_bfloat16* __restrict__ hA, float* __restrict__ feat) {
  int b = blockIdx.x;
  for (int c = threadIdx.x; c < 2048; c += 256) {
    int sec = c >> 9, j = c & 511;
    int row = (sec == 0) ? b : (sec == 1) ? 512 + b : (sec == 2) ? 256 + b : 768 + b;
    feat[b * 2048 + c] = b2f(hA[(size_t)row * 512 + j]);
  }
}

__global__ void bn_stats(const float* __restrict__ x, const float* __restrict__ g,
                         const float* __restrict__ b,
                         float* __restrict__ sc, float* __restrict__ sh) {
  int c = blockIdx.x * 256 + threadIdx.x;
  float s = 0.f, s2 = 0.f;
  for (int r = 0; r < 256; ++r) {
    float v = x[r * 2048 + c];
    s += v;
    s2 += v * v;
  }
  float mu = s * (1.f / 256.f);
  float var = s2 * (1.f / 256.f) - mu * mu;
  float rs = rsqrtf(var + 1e-5f);
  float scale = g[c] * rs;
  sc[c] = scale;
  sh[c] = b[c] - mu * scale;
}

__global__ void bn_apply(const float* __restrict__ x, const float* __restrict__ sc,
                         const float* __restrict__ sh, __hip_bfloat16* __restrict__ xn) {
  int i = blockIdx.x * 256 + threadIdx.x;
  int c = i & 2047;
  xn[i] = f2b(x[i] * sc[c] + sh[c]);
}

__global__ void final_kernel(const float* __restrict__ x2, const float* __restrict__ sc,
                             const float* __restrict__ sh, const float* __restrict__ Wo,
                             const float* __restrict__ bo, float* __restrict__ out) {
  __shared__ float red[3][256];
  int b = blockIdx.x, tid = threadIdx.x;
  float a0 = 0.f, a1 = 0.f, a2 = 0.f;
  for (int c = tid; c < 2048; c += 256) {
    float v = x2[b * 2048 + c] * sc[c] + sh[c];
    a0 += v * Wo[c];
    a1 += v * Wo[2048 + c];
    a2 += v * Wo[4096 + c];
  }
  red[0][tid] = a0; red[1][tid] = a1; red[2][tid] = a2;
  __syncthreads();
  for (int s = 128; s > 0; s >>= 1) {
    if (tid < s) {
      red[0][tid] += red[0][tid + s];
      red[1][tid] += red[1][tid + s];
      red[2][tid] += red[2][tid + s];
    }
    __syncthreads();
  }
  if (tid < 3) out[b * 3 + tid] = red[tid][0] + bo[tid];
}

// ---------------------------------------------------------------------------
extern "C" void kernel_launch(void* const* d_in, const int* in_sizes, int n_in,
                              void* d_out, int out_size, void* d_ws, size_t ws_size,
                              hipStream_t stream) {
  (void)in_sizes; (void)n_in; (void)out_size; (void)ws_size;
  const int* prem = (const int*)d_in[0];
  const int* hyp = (const int*)d_in[1];
  const float* embed = (const float*)d_in[2];
  const float* W_ih = (const float*)d_in[3];
  const float* W_hh = (const float*)d_in[4];
  const float* b_ih = (const float*)d_in[5];
  const float* b_hh = (const float*)d_in[6];
  const float* bn0g = (const float*)d_in[7];
  const float* bn0b = (const float*)d_in[8];
  const float* W0 = (const float*)d_in[9];
  const float* b0 = (const float*)d_in[10];
  const float* bn1g = (const float*)d_in[11];
  const float* bn1b = (const float*)d_in[12];
  const float* W1 = (const float*)d_in[13];
  const float* b1 = (const float*)d_in[14];
  const float* bnog = (const float*)d_in[15];
  const float* bnob = (const float*)d_in[16];
  const float* Wo = (const float*)d_in[17];
  const float* bo = (const float*)d_in[18];
  float* out = (float*)d_out;

  char* w = (char*)d_ws;
  size_t off = 0;
  auto alloc = [&](size_t bytes) {
    void* p = w + off;
    off += (bytes + 255) & ~(size_t)255;
    return p;
  };
  __hip_bfloat16* WihP = (__hip_bfloat16*)alloc((size_t)2048 * 320 * 2);
  __hip_bfloat16* Whhb = (__hip_bfloat16*)alloc((size_t)2048 * 512 * 2);
  __hip_bfloat16* W0b = (__hip_bfloat16*)alloc((size_t)2048 * 2048 * 2);
  __hip_bfloat16* W1b = (__hip_bfloat16*)alloc((size_t)2048 * 2048 * 2);
  float* biasL = (float*)alloc(2048 * 4);
  __hip_bfloat16* xp = (__hip_bfloat16*)alloc((size_t)32768 * 2048 * 2);  // 128 MiB
  size_t ain_off = off;
  __hip_bfloat16* Ain = (__hip_bfloat16*)alloc((size_t)32768 * 320 * 2);  // 20 MiB
  size_t end_off = off;
  off = ain_off;  // post-GEMM block aliases Ain (dead after xproj)
  __hip_bfloat16* hA = (__hip_bfloat16*)alloc((size_t)1024 * 512 * 2);
  __hip_bfloat16* hB = (__hip_bfloat16*)alloc((size_t)1024 * 512 * 2);
  float* cst = (float*)alloc((size_t)1024 * 512 * 4);
  float* feat = (float*)alloc((size_t)256 * 2048 * 4);
  __hip_bfloat16* xn = (__hip_bfloat16*)alloc((size_t)256 * 2048 * 2);
  float* x1 = (float*)alloc((size_t)256 * 2048 * 4);
  float* x2 = (float*)alloc((size_t)256 * 2048 * 4);
  float* sc0 = (float*)alloc(2048 * 4);
  float* sh0 = (float*)alloc(2048 * 4);
  float* sc1 = (float*)alloc(2048 * 4);
  float* sh1 = (float*)alloc(2048 * 4);
  float* sc2 = (float*)alloc(2048 * 4);
  float* sh2 = (float*)alloc(2048 * 4);
  (void)end_off;

  pack_wih<<<512, 256, 0, stream>>>(W_ih, b_ih, b_hh, WihP, biasL);
  cvt_f32_bf16<<<1024, 256, 0, stream>>>(W_hh, Whhb, 2048 * 512 / 4);
  cvt_f32_bf16<<<2048, 256, 0, stream>>>(W0, W0b, 2048 * 2048 / 4);
  cvt_f32_bf16<<<2048, 256, 0, stream>>>(W1, W1b, 2048 * 2048 / 4);
  gather_kernel<<<8192, 256, 0, stream>>>(prem, hyp, embed, Ain);
  // x_proj = combined @ W_ih^T + (b_ih + b_hh) : M=32768, N=2048, K=320
  gemm_pipe<128, 0><<<dim3(256, 16), 256, 0, stream>>>(Ain, WihP, biasL, xp, 320, 2048);
  hipMemsetAsync(hA, 0, (size_t)1024 * 512 * 2, stream);   // h0 = 0 (after GEMM: aliases Ain)
  hipMemsetAsync(cst, 0, (size_t)1024 * 512 * 4, stream);  // c0 = 0
  for (int t = 0; t < 64; ++t) {
    const __hip_bfloat16* hi = (t & 1) ? hB : hA;
    __hip_bfloat16* ho = (t & 1) ? hA : hB;
    lstm_step<<<dim3(16, 16), 256, 0, stream>>>(xp, hi, ho, cst, Whhb, t);
  }
  feat_kernel<<<256, 256, 0, stream>>>(hA, feat);  // final h in hA (t=63 odd)
  bn_stats<<<8, 256, 0, stream>>>(feat, bn0g, bn0b, sc0, sh0);
  bn_apply<<<2048, 256, 0, stream>>>(feat, sc0, sh0, xn);
  gemm_pipe<64, 1><<<dim3(4, 16), 256, 0, stream>>>(xn, W0b, b0, x1, 2048, 2048);
  bn_stats<<<8, 256, 0, stream>>>(x1, bn1g, bn1b, sc1, sh1);
  bn_apply<<<2048, 256, 0, stream>>>(x1, sc1, sh1, xn);
  gemm_pipe<64, 1><<<dim3(4, 16), 256, 0, stream>>>(xn, W1b, b1, x2, 2048, 2048);
  bn_stats<<<8, 256, 0, stream>>>(x2, bnog, bnob, sc2, sh2);
  final_kernel<<<256, 256, 0, stream>>>(x2, sc2, sh2, Wo, bo, out);
}